// Round 5
// baseline (3707.204 us; speedup 1.0000x reference)
//
#include <hip/hip_runtime.h>

#define BB 256
#define TT 2048
#define II 64
#define HH 256
#define OO 64
#define FF 16

// ---------------------------------------------------------------------------
// R9: R8 post-mortem: VGPR_Count stayed 128 -> compiler caps ARCH VGPRs at
// 128 (unified-RF split heuristic) and serves every "v"-constrained use of an
// AGPR-resident weight with a v_accvgpr_read copy (~1100 extra cyc/step/SIMD,
// VALUBusy 55% of 3734 cyc/step). Two rounds of pinning failed; design UNDER
// the cap instead:
//   * 1024 threads/block (16 waves, 4/SIMD): per-thread weights 208 -> 104
//     ints, fits the 128-VGPR budget at waves_per_eu(4,4) -> no AGPR copies.
//   * 8-way K-split x 2 rows x 2 layers/thread: 9 b128 LDS reads/wave/step
//     (144/step CU-wide), conflict-free (80B slices -> kg bases on banks
//     {0,4,..,28}, each b128 spans 4 -> exact 32-bank tiling).
//   * K-reduce pure VALU: quad_perm xor1 (0xB1), xor2 (0x4E), then
//     row_half_mirror (0x141): lane kg <-> 7-kg within each octet -> all 8
//     lanes get the full sum; no ds_swizzle, no lgkm tail.
//   * 4 waves/SIMD doubles latency hiding vs R8's 2.
// Layer pipeline unchanged: step T computes h0_T (from x_T, h0_{T-1}) and
// h1_{T-1} (from h0_{T-1}, h1_{T-2}); 1 barrier/step; double-buffered state.
// R10: R9 bench died with GPUAcquisitionTimeout (infra; kernel never ran).
// Re-audited (barrier uniformity, indexing, DPP ctrls, alignment): clean.
// Resubmitting unchanged.
// ---------------------------------------------------------------------------

// LDS per state buffer: h0 8x80 @0, h1 8x80 @640, x 8x16 @1280 -> 1408 B.
#define BUFSZ 1408
#define BUF0 0
#define BUF1 BUFSZ
#define H1OFF 640
#define XOFF 1280
#define HSL 80
#define TAILOFF (2 * BUFSZ)
#define LDSBYTES (TAILOFF + FF * HH * 2)

typedef _Float16 h8 __attribute__((ext_vector_type(8)));

// D = S0.h0*S1.h0 + S0.h1*S1.h1 + D  (v_dot2_f32_f16)
__device__ __forceinline__ void adot(float& acc, int hv, int wv) {
  asm("v_dot2_f32_f16 %0, %1, %2, %0" : "+v"(acc) : "v"(hv), "v"(wv));
}

__device__ __forceinline__ float fast_tanh(float z) {
  float e = __builtin_amdgcn_exp2f(z * 2.885390081777927f);
  return 1.0f - 2.0f * __builtin_amdgcn_rcpf(e + 1.0f);
}

__device__ __forceinline__ int pk2i(const float* p) {
  union { _Float16 h[2]; int i; } u;
  u.h[0] = (_Float16)p[0]; u.h[1] = (_Float16)p[1];
  return u.i;
}

// DPP butterfly adds. 0xB1 = quad_perm xor1, 0x4E = quad_perm xor2,
// 0x141 = row_half_mirror (lane i <-> (i&~7)|(7-(i&7)), i.e. kg <-> 7-kg):
// after xor1+xor2 the two quads of an octet are uniform, and half-mirror
// always lands in the OTHER quad -> direction-unambiguous 8-lane reduce.
template <int CTRL>
__device__ __forceinline__ float dpp_add(float v) {
  union { float f; int i; } a, r;
  a.f = v;
  r.i = __builtin_amdgcn_update_dpp(0, a.i, CTRL, 0xF, 0xF, true);
  return v + r.f;
}

// One step: layer0(T) + layer1(T-1) dots from RB, octet reduce, commit
// h0_T (lanes kg 0,1), h1_{T-1} (lanes kg 2,3), x_{T+1} into WB, 1 barrier.
#define RNN_STEP(T, RB, WB)                                                    \
  {                                                                            \
    float xn = 0.f;                                                            \
    if ((tid & 15) == 0) {                                                     \
      int tn = (T) + 1 < TT ? (T) + 1 : (T);                                   \
      xn = xrow[(size_t)tn * II + xi];                                         \
    }                                                                          \
    float a00 = 0.f, a01 = 0.f, a10 = 0.f, a11 = 0.f;                          \
    {                                                                          \
      const int4 xv = *(const int4*)(xaddr + (RB));                            \
      adot(a00, xv.x, w0x[0][0]); adot(a00, xv.y, w0x[0][1]);                  \
      adot(a00, xv.z, w0x[0][2]); adot(a00, xv.w, w0x[0][3]);                  \
      adot(a01, xv.x, w0x[1][0]); adot(a01, xv.y, w0x[1][1]);                  \
      adot(a01, xv.z, w0x[1][2]); adot(a01, xv.w, w0x[1][3]);                  \
    }                                                                          \
    _Pragma("unroll") for (int c = 0; c < 4; ++c) {                            \
      const int4 v = *(const int4*)(h0addr + (RB) + c * 16);                   \
      adot(a00, v.x, w0h[0][4 * c + 0]); adot(a00, v.y, w0h[0][4 * c + 1]);    \
      adot(a00, v.z, w0h[0][4 * c + 2]); adot(a00, v.w, w0h[0][4 * c + 3]);    \
      adot(a01, v.x, w0h[1][4 * c + 0]); adot(a01, v.y, w0h[1][4 * c + 1]);    \
      adot(a01, v.z, w0h[1][4 * c + 2]); adot(a01, v.w, w0h[1][4 * c + 3]);    \
      adot(a10, v.x, w1g[0][4 * c + 0]); adot(a10, v.y, w1g[0][4 * c + 1]);    \
      adot(a10, v.z, w1g[0][4 * c + 2]); adot(a10, v.w, w1g[0][4 * c + 3]);    \
      adot(a11, v.x, w1g[1][4 * c + 0]); adot(a11, v.y, w1g[1][4 * c + 1]);    \
      adot(a11, v.z, w1g[1][4 * c + 2]); adot(a11, v.w, w1g[1][4 * c + 3]);    \
    }                                                                          \
    _Pragma("unroll") for (int c = 0; c < 4; ++c) {                            \
      const int4 v = *(const int4*)(h0addr + (RB) + H1OFF + c * 16);           \
      adot(a10, v.x, w1h[0][4 * c + 0]); adot(a10, v.y, w1h[0][4 * c + 1]);    \
      adot(a10, v.z, w1h[0][4 * c + 2]); adot(a10, v.w, w1h[0][4 * c + 3]);    \
      adot(a11, v.x, w1h[1][4 * c + 0]); adot(a11, v.y, w1h[1][4 * c + 1]);    \
      adot(a11, v.z, w1h[1][4 * c + 2]); adot(a11, v.w, w1h[1][4 * c + 3]);    \
    }                                                                          \
    a00 = dpp_add<0xB1>(a00); a00 = dpp_add<0x4E>(a00);                        \
    a00 = dpp_add<0x141>(a00);                                                 \
    a01 = dpp_add<0xB1>(a01); a01 = dpp_add<0x4E>(a01);                        \
    a01 = dpp_add<0x141>(a01);                                                 \
    a10 = dpp_add<0xB1>(a10); a10 = dpp_add<0x4E>(a10);                        \
    a10 = dpp_add<0x141>(a10);                                                 \
    a11 = dpp_add<0xB1>(a11); a11 = dpp_add<0x4E>(a11);                        \
    a11 = dpp_add<0x141>(a11);                                                 \
    float vA = (kg & 1) ? a01 : a00;                                           \
    float vB = (kg & 1) ? a11 : a10;                                           \
    float hnew = fast_tanh(((kg & 2) ? vB : vA) + mybias);                     \
    if (kg < 4) {                                                              \
      hlast = hnew;                                                            \
      if ((T) > 0 || kg < 2) *(_Float16*)(waddr + (WB)) = (_Float16)hnew;      \
      if (kg >= 2 && (T) >= TT - FF + 1)                                       \
        *(_Float16*)(tailaddr + ((T) - (TT - FF + 1)) * (HH * 2)) =            \
            (_Float16)hnew;                                                    \
    }                                                                          \
    if ((tid & 15) == 0)                                                       \
      *(_Float16*)(lb + (WB) + XOFF + (xi >> 3) * 16 + (xi & 7) * 2) =         \
          (_Float16)xn;                                                        \
    __syncthreads();                                                           \
  }

__global__ __attribute__((amdgpu_flat_work_group_size(1024, 1024),
                          amdgpu_waves_per_eu(4, 4)))
void rnn_fused(const float* __restrict__ x, const float* __restrict__ hidden,
               const float* __restrict__ Wih0, const float* __restrict__ Whh0,
               const float* __restrict__ bih0, const float* __restrict__ bhh0,
               const float* __restrict__ Wih1, const float* __restrict__ Whh1,
               const float* __restrict__ bih1, const float* __restrict__ bhh1,
               const float* __restrict__ fcW, const float* __restrict__ fcb,
               float* __restrict__ out)
{
  const int tid = threadIdx.x;
  const int b = blockIdx.x;
  const int lane = tid & 63;
  const int kg = lane & 7;           // K-group 0..7 (32 h-elems / 8 x-elems)
  const int r0 = (tid >> 3) * 2;     // first of 2 owned rows (0..254)
  const int cj = r0 + (kg & 1);      // committed row (lanes kg<4)
  const int xi = tid >> 4;           // x element for (tid&15)==0 lanes

  __shared__ __align__(16) char lds[LDSBYTES];
  char* lb = (char*)lds;

  // ---- weights for rows r0,r0+1, K-slice kg -> 104 ints ----
  int w0x[2][4], w0h[2][16], w1g[2][16], w1h[2][16];
#pragma unroll
  for (int r = 0; r < 2; ++r) {
    const float* p0 = Wih0 + (size_t)(r0 + r) * II + kg * 8;
#pragma unroll
    for (int m = 0; m < 4; ++m) w0x[r][m] = pk2i(p0 + 2 * m);
    const float* p1 = Whh0 + (size_t)(r0 + r) * HH + kg * 32;
#pragma unroll
    for (int m = 0; m < 16; ++m) w0h[r][m] = pk2i(p1 + 2 * m);
    const float* p2 = Wih1 + (size_t)(r0 + r) * HH + kg * 32;
#pragma unroll
    for (int m = 0; m < 16; ++m) w1g[r][m] = pk2i(p2 + 2 * m);
    const float* p3 = Whh1 + (size_t)(r0 + r) * HH + kg * 32;
#pragma unroll
    for (int m = 0; m < 16; ++m) w1h[r][m] = pk2i(p3 + 2 * m);
  }
  // one-time opaque pass-through: no remat of the global loads in the loop
#pragma unroll
  for (int r = 0; r < 2; ++r) {
#pragma unroll
    for (int m = 0; m < 4; ++m) asm volatile("" : "+v"(w0x[r][m]));
#pragma unroll
    for (int m = 0; m < 16; ++m) {
      asm volatile("" : "+v"(w0h[r][m]));
      asm volatile("" : "+v"(w1g[r][m]));
      asm volatile("" : "+v"(w1h[r][m]));
    }
  }
  const int Lc = (kg >> 1) & 1;  // commit layer for kg<4 lanes
  float mybias = Lc ? (bih1[cj] + bhh1[cj]) : (bih0[cj] + bhh0[cj]);
  asm volatile("" : "+v"(mybias));

  // ---- loop-invariant LDS addresses ----
  const char* h0addr = lb + kg * HSL;        // +RB (+H1OFF) +c*16
  const char* xaddr = lb + XOFF + kg * 16;   // +RB
  char* waddr = lb + (Lc ? H1OFF : 0) + (cj >> 5) * HSL + (cj & 31) * 2;  // +WB
  char* tailaddr = lb + TAILOFF + cj * 2;    // +f*512, kg 2,3 lanes only

  // ---- init: BUF0 <- {h0_init, h1_init, x_0}; BUF1.h1 <- h1_init ----
  if (tid < HH) {
    char* p = lb + (tid >> 5) * HSL + (tid & 31) * 2;
    _Float16 h0v = (_Float16)hidden[(size_t)b * HH + tid];
    _Float16 h1v = (_Float16)hidden[(size_t)(BB + b) * HH + tid];
    *(_Float16*)(p + BUF0) = h0v;
    *(_Float16*)(p + BUF0 + H1OFF) = h1v;
    *(_Float16*)(p + BUF1 + H1OFF) = h1v;
  }
  const float* xrow = x + (size_t)b * TT * II;
  if (tid < II)
    *(_Float16*)(lb + BUF0 + XOFF + (tid >> 3) * 16 + (tid & 7) * 2) =
        (_Float16)xrow[tid];
  float hlast = 0.f;
  __syncthreads();

  // ---- main loop: 1 barrier/step, unroll x2 so RB/WB are immediates ----
#pragma unroll 1
  for (int t = 0; t < TT; t += 2) {
    RNN_STEP(t, BUF0, BUF1)
    RNN_STEP(t + 1, BUF1, BUF0)
  }

  // ---- epilogue: h1_{TT-1} from BUF0 (holds h0_{TT-1}, h1_{TT-2}) ----
  {
    float a10 = 0.f, a11 = 0.f;
#pragma unroll
    for (int c = 0; c < 4; ++c) {
      const int4 v = *(const int4*)(h0addr + BUF0 + c * 16);
      adot(a10, v.x, w1g[0][4 * c + 0]); adot(a10, v.y, w1g[0][4 * c + 1]);
      adot(a10, v.z, w1g[0][4 * c + 2]); adot(a10, v.w, w1g[0][4 * c + 3]);
      adot(a11, v.x, w1g[1][4 * c + 0]); adot(a11, v.y, w1g[1][4 * c + 1]);
      adot(a11, v.z, w1g[1][4 * c + 2]); adot(a11, v.w, w1g[1][4 * c + 3]);
    }
#pragma unroll
    for (int c = 0; c < 4; ++c) {
      const int4 v = *(const int4*)(h0addr + BUF0 + H1OFF + c * 16);
      adot(a10, v.x, w1h[0][4 * c + 0]); adot(a10, v.y, w1h[0][4 * c + 1]);
      adot(a10, v.z, w1h[0][4 * c + 2]); adot(a10, v.w, w1h[0][4 * c + 3]);
      adot(a11, v.x, w1h[1][4 * c + 0]); adot(a11, v.y, w1h[1][4 * c + 1]);
      adot(a11, v.z, w1h[1][4 * c + 2]); adot(a11, v.w, w1h[1][4 * c + 3]);
    }
    a10 = dpp_add<0xB1>(a10); a10 = dpp_add<0x4E>(a10);
    a10 = dpp_add<0x141>(a10);
    a11 = dpp_add<0xB1>(a11); a11 = dpp_add<0x4E>(a11);
    a11 = dpp_add<0x141>(a11);
    float h1e = fast_tanh(((kg & 1) ? a11 : a10) + mybias);
    if (kg == 2 || kg == 3) {
      hlast = h1e;  // h1_{TT-1}
      *(_Float16*)(tailaddr + (FF - 1) * (HH * 2)) = (_Float16)h1e;
    }
  }
  __syncthreads();

  // ---- new_hidden [2,B,H] f32 at flat offset B*F*O ----
  if (kg < 2)      out[BB * FF * OO + (size_t)b * HH + cj] = hlast;
  else if (kg < 4) out[BB * FF * OO + (size_t)(BB + b) * HH + cj] = hlast;

  // ---- out[b,f,o] = tail[f] . fcW[o,:] + fcb[o]  ([B,F,O] f32) ----
  const int o = tid & 63;
  const int f = tid >> 6;  // 0..15
  const _Float16* trow = (const _Float16*)(lb + TAILOFF) + f * HH;
  float acc = 0.f;
  const float* wrow = fcW + o * HH;
  for (int c = 0; c < HH / 8; ++c) {
    float wv[8];
#pragma unroll
    for (int k = 0; k < 8; ++k) wv[k] = wrow[8 * c + k];
    h8 q = *(const h8*)(trow + 8 * c);
#pragma unroll
    for (int e = 0; e < 8; ++e) acc += (float)q[e] * wv[e];
  }
  out[((size_t)b * FF + f) * OO + o] = acc + fcb[o];
}

extern "C" void kernel_launch(void* const* d_in, const int* in_sizes, int n_in,
                              void* d_out, int out_size, void* d_ws, size_t ws_size,
                              hipStream_t stream) {
  (void)in_sizes; (void)n_in; (void)d_ws; (void)ws_size; (void)out_size;
  rnn_fused<<<dim3(BB), dim3(1024), 0, stream>>>(
      (const float*)d_in[0],  (const float*)d_in[1],
      (const float*)d_in[2],  (const float*)d_in[3],
      (const float*)d_in[4],  (const float*)d_in[5],
      (const float*)d_in[6],  (const float*)d_in[7],
      (const float*)d_in[8],  (const float*)d_in[9],
      (const float*)d_in[10], (const float*)d_in[11],
      (float*)d_out);
}

// Round 10
// 3604.715 us; speedup vs baseline: 1.0284x; 1.0284x over previous
//
#include <hip/hip_runtime.h>

#define BB 256
#define TT 2048
#define II 64
#define HH 256
#define OO 64
#define FF 16

// ---------------------------------------------------------------------------
// R12: R11 proved v_dot2 CANNOT read AGPRs (assembler reject), and R6-R9
// proved the allocator even-splits the unified RF (arch cap = budget/2) and
// serves AGPR-resident weights with per-use v_accvgpr_read. Root problem:
// one block held ALL 416 KB of weights vs a ~256 KB usable-arch half.
// Fix: LAYER-SPLIT TWO-KERNEL PIPELINE.
//   phase 1 (rnn_l0): layer-0 recurrence only. Weights 160 KB -> 80
//     ints/thread @512thr: fits the 128 arch half -> ZERO copies. Writes the
//     full h0_t stream to workspace (bf16, 512 B/step/batch).
//   phase 2 (rnn_l1): layer-1 recurrence, streaming h0_t from ws (prefetched,
//     L2/HBM ~90us total). Weights 256 KB -> 128 ints/thread (~35-reg copy
//     tax). Tail FC fused at the end.
//   Host chunks T by TCH (largest of 2048..2 fitting ws_size) and launches
//   L0/L1 per chunk on one stream -> sequential, no cross-block sync, no
//   dispatch-order assumptions. h1 state carried in ws between chunks.
// Both kernels: 512 thr, waves_per_eu(2,2) (=> 1 block/CU, 256-reg budget),
// 8-way K-split x 4 rows/thread, pure-VALU octet reduce (dpp xor1 0xB1,
// xor2 0x4E, half_mirror 0x141), double-buffered LDS state, 1 barrier/step.
// R13-R15: three GPUAcquisitionTimeouts in a row (infra; never ran).
// Design unchanged; audits clean across three passes.
// ---------------------------------------------------------------------------

typedef _Float16 h2 __attribute__((ext_vector_type(2)));
typedef _Float16 h8 __attribute__((ext_vector_type(8)));

__device__ __forceinline__ float fdot2f(h2 a, h2 b, float c) {
  return __builtin_amdgcn_fdot2(a, b, c, false);  // v_dot2_f32_f16
}
__device__ __forceinline__ h2 i2h(int w) {
  union { int i; h2 h; } u; u.i = w; return u.h;
}
__device__ __forceinline__ int pk2i(const float* p) {
  union { h2 h; int i; } u; u.h[0] = (_Float16)p[0]; u.h[1] = (_Float16)p[1];
  return u.i;
}
__device__ __forceinline__ float fast_tanh(float z) {
  float e = __builtin_amdgcn_exp2f(z * 2.885390081777927f);
  return 1.0f - 2.0f * __builtin_amdgcn_rcpf(e + 1.0f);
}
// 0xB1 quad xor1, 0x4E quad xor2, 0x141 row_half_mirror (kg <-> 7-kg)
template <int CTRL>
__device__ __forceinline__ float dpp_add(float v) {
  union { float f; int i; } a, r;
  a.f = v;
  r.i = __builtin_amdgcn_update_dpp(0, a.i, CTRL, 0xF, 0xF, true);
  return v + r.f;
}

// =================== phase 1: layer 0 ===================
// LDS: h0 dbuf 2x(8 slices x 80B) @0; x dbuf 2x(8 x 16B) @1280. Total 1536 B.
#define P1_HB(i) ((i) * 640)
#define P1_XB(i) (1280 + (i) * 128)

#define L0_STEP(T, RB, WB)                                                     \
  {                                                                            \
    float xn = 0.f;                                                            \
    if ((tid & 7) == 0) {                                                      \
      int tg = tstart + (T) + 1; if (tg > TT - 1) tg = TT - 1;                 \
      xn = xrow[(size_t)tg * II + xi];                                         \
    }                                                                          \
    float aa[4] = {0.f, 0.f, 0.f, 0.f};                                        \
    {                                                                          \
      const int4 xv = *(const int4*)(lb + P1_XB(RB) + kg * 16);                \
      _Pragma("unroll") for (int r = 0; r < 4; ++r) {                          \
        aa[r] = fdot2f(i2h(xv.x), i2h(w0x[r][0]), aa[r]);                      \
        aa[r] = fdot2f(i2h(xv.y), i2h(w0x[r][1]), aa[r]);                      \
        aa[r] = fdot2f(i2h(xv.z), i2h(w0x[r][2]), aa[r]);                      \
        aa[r] = fdot2f(i2h(xv.w), i2h(w0x[r][3]), aa[r]);                      \
      }                                                                        \
    }                                                                          \
    _Pragma("unroll") for (int c = 0; c < 4; ++c) {                            \
      const int4 v = *(const int4*)(lb + P1_HB(RB) + kg * 80 + c * 16);        \
      _Pragma("unroll") for (int r = 0; r < 4; ++r) {                          \
        aa[r] = fdot2f(i2h(v.x), i2h(w0h[r][4 * c + 0]), aa[r]);               \
        aa[r] = fdot2f(i2h(v.y), i2h(w0h[r][4 * c + 1]), aa[r]);               \
        aa[r] = fdot2f(i2h(v.z), i2h(w0h[r][4 * c + 2]), aa[r]);               \
        aa[r] = fdot2f(i2h(v.w), i2h(w0h[r][4 * c + 3]), aa[r]);               \
      }                                                                        \
    }                                                                          \
    _Pragma("unroll") for (int r = 0; r < 4; ++r) {                            \
      aa[r] = dpp_add<0xB1>(aa[r]); aa[r] = dpp_add<0x4E>(aa[r]);              \
      aa[r] = dpp_add<0x141>(aa[r]);                                           \
    }                                                                          \
    float s0 = (kg & 1) ? aa[1] : aa[0];                                       \
    float s1 = (kg & 1) ? aa[3] : aa[2];                                       \
    float hnew = fast_tanh(((kg & 2) ? s1 : s0) + mybias);                     \
    if (kg < 4) {                                                              \
      *(_Float16*)(lb + P1_HB(WB) + (cj >> 5) * 80 + (cj & 31) * 2) =          \
          (_Float16)hnew;                                                      \
      hstream[(bt + (T)) * HH + cj] = (_Float16)hnew;                          \
      if (tstart + (T) == TT - 1) h0keep = hnew;                               \
    }                                                                          \
    if ((tid & 7) == 0)                                                        \
      *(_Float16*)(lb + P1_XB(WB) + (xi >> 3) * 16 + (xi & 7) * 2) =           \
          (_Float16)xn;                                                        \
    __syncthreads();                                                           \
  }

__global__ __attribute__((amdgpu_flat_work_group_size(512, 512),
                          amdgpu_waves_per_eu(2, 2)))
void rnn_l0(const float* __restrict__ x, const float* __restrict__ hidden,
            const float* __restrict__ Wih0, const float* __restrict__ Whh0,
            const float* __restrict__ bih0, const float* __restrict__ bhh0,
            _Float16* __restrict__ hstream, float* __restrict__ out,
            int tstart, int tcount)
{
  const int tid = threadIdx.x;
  const int b = blockIdx.x;
  const int kg = tid & 7;            // K-group (8 x-halfs / 32 h-halfs)
  const int r0 = (tid >> 3) * 4;     // first of 4 owned rows
  const int cj = r0 + (kg & 3);      // committed row (lanes kg<4)
  const int xi = tid >> 3;           // x elem for (tid&7)==0 lanes

  __shared__ __align__(16) char lds[1536];
  char* lb = (char*)lds;
  const size_t bt = (size_t)b * tcount;

  // weights: 4 rows x (x:4 + h:16) = 80 ints -> fits the 128-reg arch half
  int w0x[4][4], w0h[4][16];
#pragma unroll
  for (int r = 0; r < 4; ++r) {
    const float* p0 = Wih0 + (size_t)(r0 + r) * II + kg * 8;
#pragma unroll
    for (int m = 0; m < 4; ++m) w0x[r][m] = pk2i(p0 + 2 * m);
    const float* p1 = Whh0 + (size_t)(r0 + r) * HH + kg * 32;
#pragma unroll
    for (int m = 0; m < 16; ++m) w0h[r][m] = pk2i(p1 + 2 * m);
  }
#pragma unroll
  for (int r = 0; r < 4; ++r) {
#pragma unroll
    for (int m = 0; m < 4; ++m) asm volatile("" : "+v"(w0x[r][m]));
#pragma unroll
    for (int m = 0; m < 16; ++m) asm volatile("" : "+v"(w0h[r][m]));
  }
  float mybias = bih0[cj] + bhh0[cj];
  asm volatile("" : "+v"(mybias));

  const float* xrow = x + (size_t)b * TT * II;

  // init: h0 state (chunk0: hidden[0]; else last row of previous stream,
  // still intact since this launch only overwrites during the loop), x row
  if (tid < HH) {
    _Float16 hv = (tstart == 0)
        ? (_Float16)hidden[(size_t)b * HH + tid]
        : hstream[(bt + (tcount - 1)) * HH + tid];
    *(_Float16*)(lb + P1_HB(0) + (tid >> 5) * 80 + (tid & 31) * 2) = hv;
  }
  if (tid < II)
    *(_Float16*)(lb + P1_XB(0) + (tid >> 3) * 16 + (tid & 7) * 2) =
        (_Float16)xrow[(size_t)tstart * II + tid];
  float h0keep = 0.f;
  __syncthreads();

#pragma unroll 1
  for (int t = 0; t < tcount; t += 2) {
    L0_STEP(t, 0, 1)
    L0_STEP(t + 1, 1, 0)
  }

  if (tstart + tcount == TT && kg < 4)
    out[BB * FF * OO + (size_t)b * HH + cj] = h0keep;  // new_hidden[0], f32
}

// =================== phase 2: layer 1 + tail FC ===================
// LDS: h0in dbuf 2x640 @0; h1 dbuf 2x640 @1280; tail FFx512B @2560. 10752 B.
#define P2_GB(i) ((i) * 640)
#define P2_HB(i) (1280 + (i) * 640)
#define P2_TAIL 2560

#define L1_STEP(T, RB, WB)                                                     \
  {                                                                            \
    int gn = 0;                                                                \
    if (tid < 128) {                                                           \
      int tn = (T) + 1; if (tn > tcount - 1) tn = tcount - 1;                  \
      gn = gi[(bt + tn) * 128 + tid];                                          \
    }                                                                          \
    float aa[4] = {0.f, 0.f, 0.f, 0.f};                                        \
    _Pragma("unroll") for (int c = 0; c < 4; ++c) {                            \
      const int4 v = *(const int4*)(lb + P2_GB(RB) + kg * 80 + c * 16);        \
      _Pragma("unroll") for (int r = 0; r < 4; ++r) {                          \
        aa[r] = fdot2f(i2h(v.x), i2h(w1g[r][4 * c + 0]), aa[r]);               \
        aa[r] = fdot2f(i2h(v.y), i2h(w1g[r][4 * c + 1]), aa[r]);               \
        aa[r] = fdot2f(i2h(v.z), i2h(w1g[r][4 * c + 2]), aa[r]);               \
        aa[r] = fdot2f(i2h(v.w), i2h(w1g[r][4 * c + 3]), aa[r]);               \
      }                                                                        \
    }                                                                          \
    _Pragma("unroll") for (int c = 0; c < 4; ++c) {                            \
      const int4 v = *(const int4*)(lb + P2_HB(RB) + kg * 80 + c * 16);        \
      _Pragma("unroll") for (int r = 0; r < 4; ++r) {                          \
        aa[r] = fdot2f(i2h(v.x), i2h(w1h[r][4 * c + 0]), aa[r]);               \
        aa[r] = fdot2f(i2h(v.y), i2h(w1h[r][4 * c + 1]), aa[r]);               \
        aa[r] = fdot2f(i2h(v.z), i2h(w1h[r][4 * c + 2]), aa[r]);               \
        aa[r] = fdot2f(i2h(v.w), i2h(w1h[r][4 * c + 3]), aa[r]);               \
      }                                                                        \
    }                                                                          \
    _Pragma("unroll") for (int r = 0; r < 4; ++r) {                            \
      aa[r] = dpp_add<0xB1>(aa[r]); aa[r] = dpp_add<0x4E>(aa[r]);              \
      aa[r] = dpp_add<0x141>(aa[r]);                                           \
    }                                                                          \
    float s0 = (kg & 1) ? aa[1] : aa[0];                                       \
    float s1 = (kg & 1) ? aa[3] : aa[2];                                       \
    float hnew = fast_tanh(((kg & 2) ? s1 : s0) + mybias);                     \
    if (kg < 4) {                                                              \
      *(_Float16*)(lb + P2_HB(WB) + (cj >> 5) * 80 + (cj & 31) * 2) =          \
          (_Float16)hnew;                                                      \
      if (lastchunk && (T) >= tcount - FF)                                     \
        *(_Float16*)(lb + P2_TAIL + ((T) - (tcount - FF)) * 512 + cj * 2) =    \
            (_Float16)hnew;                                                    \
      if (lastchunk && (T) == tcount - 1) h1keep = hnew;                       \
    }                                                                          \
    if (tid < 128)                                                             \
      *(int*)(lb + P2_GB(WB) + (tid >> 4) * 80 + (tid & 15) * 4) = gn;         \
    __syncthreads();                                                           \
  }

__global__ __attribute__((amdgpu_flat_work_group_size(512, 512),
                          amdgpu_waves_per_eu(2, 2)))
void rnn_l1(const float* __restrict__ hidden, const float* __restrict__ Wih1,
            const float* __restrict__ Whh1, const float* __restrict__ bih1,
            const float* __restrict__ bhh1, const float* __restrict__ fcW,
            const float* __restrict__ fcb, const _Float16* __restrict__ hstream,
            _Float16* __restrict__ h1carry, float* __restrict__ out,
            int tstart, int tcount)
{
  const int tid = threadIdx.x;
  const int b = blockIdx.x;
  const int kg = tid & 7;
  const int r0 = (tid >> 3) * 4;
  const int cj = r0 + (kg & 3);
  const bool lastchunk = (tstart + tcount == TT);

  __shared__ __align__(16) char lds[10752];
  char* lb = (char*)lds;
  const size_t bt = (size_t)b * tcount;
  const int* gi = (const int*)hstream;

  // weights: 4 rows x (g:16 + h:16) = 128 ints (~35 spill into AGPR half)
  int w1g[4][16], w1h[4][16];
#pragma unroll
  for (int r = 0; r < 4; ++r) {
    const float* p2 = Wih1 + (size_t)(r0 + r) * HH + kg * 32;
#pragma unroll
    for (int m = 0; m < 16; ++m) w1g[r][m] = pk2i(p2 + 2 * m);
    const float* p3 = Whh1 + (size_t)(r0 + r) * HH + kg * 32;
#pragma unroll
    for (int m = 0; m < 16; ++m) w1h[r][m] = pk2i(p3 + 2 * m);
  }
#pragma unroll
  for (int r = 0; r < 4; ++r) {
#pragma unroll
    for (int m = 0; m < 16; ++m) {
      asm volatile("" : "+v"(w1g[r][m]));
      asm volatile("" : "+v"(w1h[r][m]));
    }
  }
  float mybias = bih1[cj] + bhh1[cj];
  asm volatile("" : "+v"(mybias));

  // init: h1 state (chunk0: hidden[1]; else carry), h0in row 0
  if (tid < HH) {
    _Float16 hv = (tstart == 0)
        ? (_Float16)hidden[(size_t)(BB + b) * HH + tid]
        : h1carry[(size_t)b * HH + tid];
    *(_Float16*)(lb + P2_HB(0) + (tid >> 5) * 80 + (tid & 31) * 2) = hv;
  }
  if (tid < 128)
    *(int*)(lb + P2_GB(0) + (tid >> 4) * 80 + (tid & 15) * 4) = gi[bt * 128 + tid];
  float h1keep = 0.f;
  __syncthreads();

#pragma unroll 1
  for (int t = 0; t < tcount; t += 2) {
    L1_STEP(t, 0, 1)
    L1_STEP(t + 1, 1, 0)
  }

  // carry h1 state (final state is in buffer 0: tcount even)
  if (tid < HH)
    h1carry[(size_t)b * HH + tid] =
        *(_Float16*)(lb + P2_HB(0) + (tid >> 5) * 80 + (tid & 31) * 2);

  if (!lastchunk) return;

  // new_hidden[1], f32-accurate
  if (kg < 4) out[BB * FF * OO + (size_t)(BB + b) * HH + cj] = h1keep;

  // out[b,f,o] = tail[f] . fcW[o,:] + fcb[o]
  const int o = tid & 63;
  const int fg = tid >> 6;  // f = 2*fg, 2*fg+1
  const _Float16* tp = (const _Float16*)(lb + P2_TAIL);
  float acc0 = 0.f, acc1 = 0.f;
  const float* wrow = fcW + o * HH;
  for (int c = 0; c < HH / 8; ++c) {
    float wv[8];
#pragma unroll
    for (int k = 0; k < 8; ++k) wv[k] = wrow[8 * c + k];
    h8 q0 = *(const h8*)(tp + (2 * fg) * HH + 8 * c);
    h8 q1 = *(const h8*)(tp + (2 * fg + 1) * HH + 8 * c);
#pragma unroll
    for (int e = 0; e < 8; ++e) {
      acc0 += (float)q0[e] * wv[e];
      acc1 += (float)q1[e] * wv[e];
    }
  }
  const float bo = fcb[o];
  out[((size_t)b * FF + 2 * fg) * OO + o] = acc0 + bo;
  out[((size_t)b * FF + 2 * fg + 1) * OO + o] = acc1 + bo;
}

extern "C" void kernel_launch(void* const* d_in, const int* in_sizes, int n_in,
                              void* d_out, int out_size, void* d_ws, size_t ws_size,
                              hipStream_t stream) {
  (void)in_sizes; (void)n_in; (void)out_size;
  const float* x    = (const float*)d_in[0];
  const float* hid  = (const float*)d_in[1];
  const float* Wih0 = (const float*)d_in[2];
  const float* Whh0 = (const float*)d_in[3];
  const float* bih0 = (const float*)d_in[4];
  const float* bhh0 = (const float*)d_in[5];
  const float* Wih1 = (const float*)d_in[6];
  const float* Whh1 = (const float*)d_in[7];
  const float* bih1 = (const float*)d_in[8];
  const float* bhh1 = (const float*)d_in[9];
  const float* fcW  = (const float*)d_in[10];
  const float* fcb  = (const float*)d_in[11];
  float* out = (float*)d_out;

  // largest even chunk whose h0-stream + h1-carry fits the workspace
  size_t tch = 2048;
  while (tch > 2 &&
         ((size_t)BB * tch * HH * 2 + (size_t)BB * HH * 2) > ws_size)
    tch >>= 1;
  _Float16* hstream = (_Float16*)d_ws;
  _Float16* h1carry = (_Float16*)d_ws + (size_t)BB * tch * HH;

  for (int ts = 0; ts < TT; ts += (int)tch) {
    rnn_l0<<<dim3(BB), dim3(512), 0, stream>>>(
        x, hid, Wih0, Whh0, bih0, bhh0, hstream, out, ts, (int)tch);
    rnn_l1<<<dim3(BB), dim3(512), 0, stream>>>(
        hid, Wih1, Whh1, bih1, bhh1, fcW, fcb, hstream, h1carry, out,
        ts, (int)tch);
  }
}